// Round 1
// baseline (584.181 us; speedup 1.0000x reference)
//
#include <hip/hip_runtime.h>
#include <hip/hip_bf16.h>
#include <stdint.h>

#define NTOK   8192
#define DM     1024
#define DFF    1024
#define NEXP   64
#define TOPK   2
#define NEXPAND (NTOK*TOPK)   // 16384
#define CAP    512            // (2*N)/E

typedef __attribute__((ext_vector_type(4))) float f32x4;
typedef __attribute__((ext_vector_type(8))) short bf16x8;
typedef __attribute__((ext_vector_type(4))) short short4v;

__device__ __forceinline__ short f2bf(float f) {
  __hip_bfloat16 h = __float2bfloat16(f);
  union { __hip_bfloat16 h; short s; } u; u.h = h; return u.s;
}
__device__ __forceinline__ float bf2f(short s) {
  union { float f; uint32_t u; } u; u.u = ((uint32_t)(uint16_t)s) << 16; return u.f;
}

__device__ __forceinline__ void gload16(const void* g, void* l) {
  __builtin_amdgcn_global_load_lds(
      (const __attribute__((address_space(1))) unsigned int*)g,
      (__attribute__((address_space(3))) unsigned int*)l, 16, 0, 0);
}

// ---------------- routing: exact sequential per-expert cumcount ----------------
__global__ __launch_bounds__(256) void k_route(const int* __restrict__ idx,
                                               int* __restrict__ slot_token,
                                               int* __restrict__ comb_slot) {
  const int ee = blockIdx.x;
  const int tid = threadIdx.x;
  const int lane = tid & 63;
  const int wv = tid >> 6;
  __shared__ int wsum[4];
  int base = 0;
  for (int it = 0; it < NEXPAND / 256; ++it) {
    int i = it * 256 + tid;
    bool m = (idx[i] == ee);
    unsigned long long bal = __ballot(m);
    int pre = __popcll(bal & ((1ull << lane) - 1ull));
    int wtot = __popcll(bal);
    if (lane == 0) wsum[wv] = wtot;
    __syncthreads();
    int wbase = 0, tot = 0;
#pragma unroll
    for (int w = 0; w < 4; ++w) { if (w < wv) wbase += wsum[w]; tot += wsum[w]; }
    if (m) {
      int pos = base + wbase + pre;
      if (pos < CAP) {
        comb_slot[i] = ee * CAP + pos;
        slot_token[ee * CAP + pos] = i >> 1;   // token index (k=2)
      } else {
        comb_slot[i] = -1;                      // dropped over capacity
      }
    }
    base += tot;
    __syncthreads();
  }
  int filled = base < CAP ? base : CAP;
  for (int p = filled + tid; p < CAP; p += 256) slot_token[ee * CAP + p] = -1;
}

// ---------------- dispatch: gather + f32->bf16 ----------------
__global__ __launch_bounds__(256) void k_dispatch(const float* __restrict__ hidden,
                                                  const int* __restrict__ slot_token,
                                                  short* __restrict__ xd) {
  int row = blockIdx.x;
  int tok = slot_token[row];
  int c = threadIdx.x * 4;
  short4v v;
  if (tok >= 0) {
    float4 f = *(const float4*)(hidden + (size_t)tok * DM + c);
    v[0] = f2bf(f.x); v[1] = f2bf(f.y); v[2] = f2bf(f.z); v[3] = f2bf(f.w);
  } else {
    v[0] = 0; v[1] = 0; v[2] = 0; v[3] = 0;
  }
  *(short4v*)(xd + (size_t)row * DM + c) = v;
}

// ---------------- GEMM1: act = silu(x@Wg) * (x@Wu), fused ----------------
// tile: 128 rows x 64 act-cols, BK=64, 4 waves (each 64x32)
__global__ __launch_bounds__(256) void k_gemm1(const short* __restrict__ xd,
                                               const float* __restrict__ gup,
                                               short* __restrict__ act) {
  __shared__ short As[128 * 64];
  __shared__ short Bg[64 * 64];
  __shared__ short Bu[64 * 64];
  const int bid = blockIdx.x;
  const int e  = bid >> 6;
  const int mt = (bid >> 4) & 3;
  const int nt = bid & 15;
  const int tid = threadIdx.x;
  const int lane = tid & 63;
  const int wid = tid >> 6;
  const int wm = wid >> 1;
  const int wn = wid & 1;

  const short* Abase = xd + (size_t)(e * CAP + mt * 128) * DM;
  const float* Wg = gup + (size_t)e * DM * (2 * DFF) + nt * 64;

  const int n2 = tid & 31;   // n-pair within 64-col tile
  const int kg = tid >> 5;   // 0..7 k-group

  f32x4 accg[4][2], accu[4][2];
#pragma unroll
  for (int m = 0; m < 4; ++m)
#pragma unroll
    for (int n = 0; n < 2; ++n) { accg[m][n] = (f32x4)0.f; accu[m][n] = (f32x4)0.f; }

  for (int k0 = 0; k0 < DM; k0 += 64) {
    // A: async global->LDS, 16B per lane, linear dest
#pragma unroll
    for (int q = 0; q < 4; ++q) {
      int c = wid * 4 + q;
      const short* ga = Abase + (size_t)(c * 8 + (lane >> 3)) * DM + k0 + (lane & 7) * 8;
      gload16(ga, &As[c * 512]);
    }
    // B: k-column gather (coalesced across lanes), pack bf16, write [n][k]
    const float* gq = Wg + (size_t)(k0 + kg * 8) * (2 * DFF) + n2 * 2;
    float2 gv[8], uv[8];
#pragma unroll
    for (int j = 0; j < 8; ++j) {
      gv[j] = *(const float2*)(gq + (size_t)j * (2 * DFF));
      uv[j] = *(const float2*)(gq + (size_t)j * (2 * DFF) + DFF);
    }
    bf16x8 w0 = { f2bf(gv[0].x), f2bf(gv[1].x), f2bf(gv[2].x), f2bf(gv[3].x),
                  f2bf(gv[4].x), f2bf(gv[5].x), f2bf(gv[6].x), f2bf(gv[7].x) };
    bf16x8 w1 = { f2bf(gv[0].y), f2bf(gv[1].y), f2bf(gv[2].y), f2bf(gv[3].y),
                  f2bf(gv[4].y), f2bf(gv[5].y), f2bf(gv[6].y), f2bf(gv[7].y) };
    bf16x8 w2 = { f2bf(uv[0].x), f2bf(uv[1].x), f2bf(uv[2].x), f2bf(uv[3].x),
                  f2bf(uv[4].x), f2bf(uv[5].x), f2bf(uv[6].x), f2bf(uv[7].x) };
    bf16x8 w3 = { f2bf(uv[0].y), f2bf(uv[1].y), f2bf(uv[2].y), f2bf(uv[3].y),
                  f2bf(uv[4].y), f2bf(uv[5].y), f2bf(uv[6].y), f2bf(uv[7].y) };
    *(bf16x8*)&Bg[(n2 * 2 + 0) * 64 + kg * 8] = w0;
    *(bf16x8*)&Bg[(n2 * 2 + 1) * 64 + kg * 8] = w1;
    *(bf16x8*)&Bu[(n2 * 2 + 0) * 64 + kg * 8] = w2;
    *(bf16x8*)&Bu[(n2 * 2 + 1) * 64 + kg * 8] = w3;
    __syncthreads();
#pragma unroll
    for (int kh = 0; kh < 2; ++kh) {
      const int kb = kh * 32 + (lane >> 4) * 8;
      bf16x8 a[4], bg[2], bu[2];
#pragma unroll
      for (int m = 0; m < 4; ++m)
        a[m] = *(const bf16x8*)&As[(wm * 64 + m * 16 + (lane & 15)) * 64 + kb];
#pragma unroll
      for (int n = 0; n < 2; ++n) {
        bg[n] = *(const bf16x8*)&Bg[(wn * 32 + n * 16 + (lane & 15)) * 64 + kb];
        bu[n] = *(const bf16x8*)&Bu[(wn * 32 + n * 16 + (lane & 15)) * 64 + kb];
      }
#pragma unroll
      for (int m = 0; m < 4; ++m)
#pragma unroll
        for (int n = 0; n < 2; ++n) {
          accg[m][n] = __builtin_amdgcn_mfma_f32_16x16x32_bf16(a[m], bg[n], accg[m][n], 0, 0, 0);
          accu[m][n] = __builtin_amdgcn_mfma_f32_16x16x32_bf16(a[m], bu[n], accu[m][n], 0, 0, 0);
        }
    }
    __syncthreads();
  }
  // fused SwiGLU epilogue -> act bf16
  short* obase = act + (size_t)(e * CAP + mt * 128) * DFF + nt * 64;
#pragma unroll
  for (int m = 0; m < 4; ++m)
#pragma unroll
    for (int n = 0; n < 2; ++n)
#pragma unroll
      for (int j = 0; j < 4; ++j) {
        int rl = wm * 64 + m * 16 + (lane >> 4) * 4 + j;
        int cl = wn * 32 + n * 16 + (lane & 15);
        float g = accg[m][n][j];
        float u = accu[m][n][j];
        float s = (g / (1.f + __expf(-g))) * u;
        obase[(size_t)rl * DFF + cl] = f2bf(s);
      }
}

// ---------------- GEMM2: yd = act @ down ----------------
// tile: 128 x 128, BK=64, 4 waves (each 64x64)
__global__ __launch_bounds__(256) void k_gemm2(const short* __restrict__ act,
                                               const float* __restrict__ down,
                                               float* __restrict__ yd) {
  __shared__ short As[128 * 64];
  __shared__ short Bt[128 * 64];
  const int bid = blockIdx.x;
  const int e  = bid >> 5;
  const int mt = (bid >> 3) & 3;
  const int nt = bid & 7;
  const int tid = threadIdx.x;
  const int lane = tid & 63;
  const int wid = tid >> 6;
  const int wm = wid >> 1;
  const int wn = wid & 1;

  const short* Abase = act + (size_t)(e * CAP + mt * 128) * DFF;
  const float* Wb = down + (size_t)e * DFF * DM + nt * 128;

  f32x4 acc[4][4];
#pragma unroll
  for (int m = 0; m < 4; ++m)
#pragma unroll
    for (int n = 0; n < 4; ++n) acc[m][n] = (f32x4)0.f;

  for (int k0 = 0; k0 < DFF; k0 += 64) {
#pragma unroll
    for (int q = 0; q < 4; ++q) {
      int c = wid * 4 + q;
      const short* ga = Abase + (size_t)(c * 8 + (lane >> 3)) * DFF + k0 + (lane & 7) * 8;
      gload16(ga, &As[c * 512]);
    }
#pragma unroll
    for (int rr = 0; rr < 2; ++rr) {
      int task = rr * 256 + tid;
      int n2 = task & 63;
      int kgr = task >> 6;
      const float* bq = Wb + (size_t)(k0 + kgr * 8) * DM + n2 * 2;
      float2 bv[8];
#pragma unroll
      for (int j = 0; j < 8; ++j) bv[j] = *(const float2*)(bq + (size_t)j * DM);
      bf16x8 w0 = { f2bf(bv[0].x), f2bf(bv[1].x), f2bf(bv[2].x), f2bf(bv[3].x),
                    f2bf(bv[4].x), f2bf(bv[5].x), f2bf(bv[6].x), f2bf(bv[7].x) };
      bf16x8 w1 = { f2bf(bv[0].y), f2bf(bv[1].y), f2bf(bv[2].y), f2bf(bv[3].y),
                    f2bf(bv[4].y), f2bf(bv[5].y), f2bf(bv[6].y), f2bf(bv[7].y) };
      *(bf16x8*)&Bt[(n2 * 2 + 0) * 64 + kgr * 8] = w0;
      *(bf16x8*)&Bt[(n2 * 2 + 1) * 64 + kgr * 8] = w1;
    }
    __syncthreads();
#pragma unroll
    for (int kh = 0; kh < 2; ++kh) {
      const int kb = kh * 32 + (lane >> 4) * 8;
      bf16x8 a[4], b[4];
#pragma unroll
      for (int m = 0; m < 4; ++m)
        a[m] = *(const bf16x8*)&As[(wm * 64 + m * 16 + (lane & 15)) * 64 + kb];
#pragma unroll
      for (int n = 0; n < 4; ++n)
        b[n] = *(const bf16x8*)&Bt[(wn * 64 + n * 16 + (lane & 15)) * 64 + kb];
#pragma unroll
      for (int m = 0; m < 4; ++m)
#pragma unroll
        for (int n = 0; n < 4; ++n)
          acc[m][n] = __builtin_amdgcn_mfma_f32_16x16x32_bf16(a[m], b[n], acc[m][n], 0, 0, 0);
    }
    __syncthreads();
  }
  float* obase = yd + (size_t)(e * CAP + mt * 128) * DM + nt * 128;
#pragma unroll
  for (int m = 0; m < 4; ++m)
#pragma unroll
    for (int n = 0; n < 4; ++n)
#pragma unroll
      for (int j = 0; j < 4; ++j) {
        int rl = wm * 64 + m * 16 + (lane >> 4) * 4 + j;
        int cl = wn * 64 + n * 16 + (lane & 15);
        obase[(size_t)rl * DM + cl] = acc[m][n][j];
      }
}

// ---------------- combine: out[t] = sum_k w_k * yd[slot_k] ----------------
__global__ __launch_bounds__(256) void k_combine(const int* __restrict__ comb_slot,
                                                 const float* __restrict__ topw,
                                                 const float* __restrict__ yd,
                                                 float* __restrict__ out) {
  int t = blockIdx.x;
  int c = threadIdx.x * 4;
  f32x4 acc = (f32x4)0.f;
#pragma unroll
  for (int j = 0; j < 2; ++j) {
    int s = comb_slot[2 * t + j];
    if (s >= 0) {
      float w = topw[2 * t + j];
      f32x4 v = *(const f32x4*)(yd + (size_t)s * DM + c);
      acc += w * v;
    }
  }
  *(f32x4*)(out + (size_t)t * DM + c) = acc;
}

extern "C" void kernel_launch(void* const* d_in, const int* in_sizes, int n_in,
                              void* d_out, int out_size, void* d_ws, size_t ws_size,
                              hipStream_t stream) {
  const float* hidden = (const float*)d_in[0];
  const int*   idx    = (const int*)d_in[1];
  const float* topw   = (const float*)d_in[2];
  const float* gup    = (const float*)d_in[3];
  const float* down   = (const float*)d_in[4];
  float* out = (float*)d_out;

  char* ws = (char*)d_ws;
  int*   slot_token = (int*)ws;                                   // E*C   = 128KB
  int*   comb_slot  = (int*)(ws + 131072);                        // N     = 64KB
  short* xd  = (short*)(ws + 131072 + 65536);                     // 64MB bf16
  short* act = xd + (size_t)NEXP * CAP * DM;                      // 64MB bf16
  float* yd  = (float*)(act + (size_t)NEXP * CAP * DFF);          // 128MB f32

  k_route<<<NEXP, 256, 0, stream>>>(idx, slot_token, comb_slot);
  k_dispatch<<<NEXP * CAP, 256, 0, stream>>>(hidden, slot_token, xd);
  k_gemm1<<<NEXP * 64, 256, 0, stream>>>(xd, gup, act);
  k_gemm2<<<NEXP * 32, 256, 0, stream>>>(act, down, yd);
  k_combine<<<NTOK, 256, 0, stream>>>(comb_slot, topw, yd, out);
}

// Round 2
// 478.944 us; speedup vs baseline: 1.2197x; 1.2197x over previous
//
#include <hip/hip_runtime.h>
#include <hip/hip_bf16.h>
#include <stdint.h>

#define NTOK   8192
#define DM     1024
#define DFF    1024
#define NEXP   64
#define TOPK   2
#define NEXPAND (NTOK*TOPK)   // 16384
#define CAP    512            // (2*N)/E

typedef __attribute__((ext_vector_type(4))) float f32x4;
typedef __attribute__((ext_vector_type(8))) short bf16x8;
typedef __attribute__((ext_vector_type(4))) short short4v;

__device__ __forceinline__ short f2bf(float f) {
  __hip_bfloat16 h = __float2bfloat16(f);
  union { __hip_bfloat16 h; short s; } u; u.h = h; return u.s;
}

__device__ __forceinline__ void gload16(const void* g, void* l) {
  __builtin_amdgcn_global_load_lds(
      (const __attribute__((address_space(1))) unsigned int*)g,
      (__attribute__((address_space(3))) unsigned int*)l, 16, 0, 0);
}

// ---------------- routing: exact sequential per-expert cumcount ----------------
__global__ __launch_bounds__(256) void k_route(const int* __restrict__ idx,
                                               int* __restrict__ slot_token,
                                               int* __restrict__ comb_slot) {
  const int ee = blockIdx.x;
  const int tid = threadIdx.x;
  const int lane = tid & 63;
  const int wv = tid >> 6;
  __shared__ int wsum[4];
  int base = 0;
  for (int it = 0; it < NEXPAND / 256; ++it) {
    int i = it * 256 + tid;
    bool m = (idx[i] == ee);
    unsigned long long bal = __ballot(m);
    int pre = __popcll(bal & ((1ull << lane) - 1ull));
    int wtot = __popcll(bal);
    if (lane == 0) wsum[wv] = wtot;
    __syncthreads();
    int wbase = 0, tot = 0;
#pragma unroll
    for (int w = 0; w < 4; ++w) { if (w < wv) wbase += wsum[w]; tot += wsum[w]; }
    if (m) {
      int pos = base + wbase + pre;
      if (pos < CAP) {
        comb_slot[i] = ee * CAP + pos;
        slot_token[ee * CAP + pos] = i >> 1;   // token index (k=2)
      } else {
        comb_slot[i] = -1;                      // dropped over capacity
      }
    }
    base += tot;
    __syncthreads();
  }
  int filled = base < CAP ? base : CAP;
  for (int p = filled + tid; p < CAP; p += 256) slot_token[ee * CAP + p] = -1;
}

// ---------------- dispatch: gather + f32->bf16 ----------------
__global__ __launch_bounds__(256) void k_dispatch(const float* __restrict__ hidden,
                                                  const int* __restrict__ slot_token,
                                                  short* __restrict__ xd) {
  int row = blockIdx.x;
  int tok = slot_token[row];
  int c = threadIdx.x * 4;
  short4v v;
  if (tok >= 0) {
    float4 f = *(const float4*)(hidden + (size_t)tok * DM + c);
    v[0] = f2bf(f.x); v[1] = f2bf(f.y); v[2] = f2bf(f.z); v[3] = f2bf(f.w);
  } else {
    v[0] = 0; v[1] = 0; v[2] = 0; v[3] = 0;
  }
  *(short4v*)(xd + (size_t)row * DM + c) = v;
}

// LDS tile addressing (all tiles are [row][64 bf16] = 128B rows):
//   physical chunk = logical chunk ^ (row & 7); chunk = 8 bf16 = 16B.
// A tiles are DMA'd (linear dest) -> pre-swizzle the GLOBAL source column.
// B tiles: ds_write/ds_read both apply the XOR.

// ---------------- GEMM1: act = silu(x@Wg) * (x@Wu), fused ----------------
// tile: 128 rows x 64 act-cols (gate+up), BK=64, 4 waves
__global__ __launch_bounds__(256) void k_gemm1(const short* __restrict__ xd,
                                               const float* __restrict__ gup,
                                               short* __restrict__ act) {
  __shared__ short As[128 * 64];
  __shared__ short Bg[64 * 64];
  __shared__ short Bu[64 * 64];
  int bid0 = blockIdx.x;
  int bid = (bid0 & 7) * (NEXP * 64 / 8) + (bid0 >> 3);   // XCD chunked swizzle
  const int e  = bid >> 6;
  const int mt = (bid >> 4) & 3;
  const int nt = bid & 15;
  const int tid = threadIdx.x;
  const int lane = tid & 63;
  const int wid = tid >> 6;
  const int wm = wid >> 1;
  const int wn = wid & 1;

  const short* Abase = xd + (size_t)(e * CAP + mt * 128) * DM;
  const float* Wg = gup + (size_t)e * DM * (2 * DFF) + nt * 64;

  // A staging geometry (per thread, 4 DMA ops): row = c*8 + (lane>>3)
  const int arow = lane >> 3;                 // row&7 within 8-row group
  const int acol = ((lane & 7) ^ arow) * 8;   // pre-swizzled source chunk

  // B gather geometry: one column per lane, wave = k-quarter (16 rows)
  const int bn = lane;        // column 0..63
  const int bh = wid;         // k rows bh*16 .. bh*16+15
  const int bsw = (bn & 7);
  const int bwb = bn * 64;

  f32x4 accg[4][2], accu[4][2];
#pragma unroll
  for (int m = 0; m < 4; ++m)
#pragma unroll
    for (int n = 0; n < 2; ++n) { accg[m][n] = (f32x4)0.f; accu[m][n] = (f32x4)0.f; }

  for (int k0 = 0; k0 < DM; k0 += 64) {
    // A: async global->LDS, 16B/lane, swizzled source
#pragma unroll
    for (int q = 0; q < 4; ++q) {
      int c = wid * 4 + q;
      const short* ga = Abase + (size_t)(c * 8 + arow) * DM + k0 + acol;
      gload16(ga, &As[c * 512]);
    }
    // B: per-column gather (coalesced 256B/row across lanes), pack, swizzled write
    const float* gq = Wg + (size_t)(k0 + bh * 16) * (2 * DFF) + bn;
    float gv[16], uv[16];
#pragma unroll
    for (int j = 0; j < 16; ++j) {
      gv[j] = gq[(size_t)j * (2 * DFF)];
      uv[j] = gq[(size_t)j * (2 * DFF) + DFF];
    }
    bf16x8 wg0 = { f2bf(gv[0]), f2bf(gv[1]), f2bf(gv[2]), f2bf(gv[3]),
                   f2bf(gv[4]), f2bf(gv[5]), f2bf(gv[6]), f2bf(gv[7]) };
    bf16x8 wg1 = { f2bf(gv[8]), f2bf(gv[9]), f2bf(gv[10]), f2bf(gv[11]),
                   f2bf(gv[12]), f2bf(gv[13]), f2bf(gv[14]), f2bf(gv[15]) };
    bf16x8 wu0 = { f2bf(uv[0]), f2bf(uv[1]), f2bf(uv[2]), f2bf(uv[3]),
                   f2bf(uv[4]), f2bf(uv[5]), f2bf(uv[6]), f2bf(uv[7]) };
    bf16x8 wu1 = { f2bf(uv[8]), f2bf(uv[9]), f2bf(uv[10]), f2bf(uv[11]),
                   f2bf(uv[12]), f2bf(uv[13]), f2bf(uv[14]), f2bf(uv[15]) };
    *(bf16x8*)&Bg[bwb + ((bh * 2)     ^ bsw) * 8] = wg0;
    *(bf16x8*)&Bg[bwb + ((bh * 2 + 1) ^ bsw) * 8] = wg1;
    *(bf16x8*)&Bu[bwb + ((bh * 2)     ^ bsw) * 8] = wu0;
    *(bf16x8*)&Bu[bwb + ((bh * 2 + 1) ^ bsw) * 8] = wu1;
    __syncthreads();
#pragma unroll
    for (int kh = 0; kh < 2; ++kh) {
      const int kq = kh * 4 + (lane >> 4);        // logical chunk 0..7
      const int co = (kq ^ (lane & 7)) * 8;       // swizzled byte/2 offset
      bf16x8 a[4], bgf[2], buf_[2];
#pragma unroll
      for (int m = 0; m < 4; ++m)
        a[m] = *(const bf16x8*)&As[(wm * 64 + m * 16 + (lane & 15)) * 64 + co];
#pragma unroll
      for (int n = 0; n < 2; ++n) {
        bgf[n]  = *(const bf16x8*)&Bg[(wn * 32 + n * 16 + (lane & 15)) * 64 + co];
        buf_[n] = *(const bf16x8*)&Bu[(wn * 32 + n * 16 + (lane & 15)) * 64 + co];
      }
#pragma unroll
      for (int m = 0; m < 4; ++m)
#pragma unroll
        for (int n = 0; n < 2; ++n) {
          accg[m][n] = __builtin_amdgcn_mfma_f32_16x16x32_bf16(a[m], bgf[n], accg[m][n], 0, 0, 0);
          accu[m][n] = __builtin_amdgcn_mfma_f32_16x16x32_bf16(a[m], buf_[n], accu[m][n], 0, 0, 0);
        }
    }
    __syncthreads();
  }
  // fused SwiGLU epilogue -> act bf16
  short* obase = act + (size_t)(e * CAP + mt * 128) * DFF + nt * 64;
#pragma unroll
  for (int m = 0; m < 4; ++m)
#pragma unroll
    for (int n = 0; n < 2; ++n)
#pragma unroll
      for (int j = 0; j < 4; ++j) {
        int rl = wm * 64 + m * 16 + (lane >> 4) * 4 + j;
        int cl = wn * 32 + n * 16 + (lane & 15);
        float g = accg[m][n][j];
        float u = accu[m][n][j];
        float s = (g / (1.f + __expf(-g))) * u;
        obase[(size_t)rl * DFF + cl] = f2bf(s);
      }
}

// ---------------- GEMM2: yd = act @ down ----------------
// tile: 128 x 128, BK=64, 4 waves (each 64x64)
__global__ __launch_bounds__(256) void k_gemm2(const short* __restrict__ act,
                                               const float* __restrict__ down,
                                               float* __restrict__ yd) {
  __shared__ short As[128 * 64];
  __shared__ short Bt[128 * 64];
  int bid0 = blockIdx.x;
  int bid = (bid0 & 7) * (NEXP * 32 / 8) + (bid0 >> 3);   // XCD chunked swizzle
  const int e  = bid >> 5;
  const int mt = (bid >> 3) & 3;
  const int nt = bid & 7;
  const int tid = threadIdx.x;
  const int lane = tid & 63;
  const int wid = tid >> 6;
  const int wm = wid >> 1;
  const int wn = wid & 1;

  const short* Abase = act + (size_t)(e * CAP + mt * 128) * DFF;
  const float* Wb = down + (size_t)e * DFF * DM + nt * 128;

  const int arow = lane >> 3;
  const int acol = ((lane & 7) ^ arow) * 8;

  f32x4 acc[4][4];
#pragma unroll
  for (int m = 0; m < 4; ++m)
#pragma unroll
    for (int n = 0; n < 4; ++n) acc[m][n] = (f32x4)0.f;

  for (int k0 = 0; k0 < DFF; k0 += 64) {
#pragma unroll
    for (int q = 0; q < 4; ++q) {
      int c = wid * 4 + q;
      const short* ga = Abase + (size_t)(c * 8 + arow) * DFF + k0 + acol;
      gload16(ga, &As[c * 512]);
    }
    // B: per-column gather; two rounds cover 128 cols x 4 k-quarters
#pragma unroll
    for (int r = 0; r < 2; ++r) {
      const int bn = r * 64 + lane;
      const float* bq = Wb + (size_t)(k0 + wid * 16) * DM + bn;
      float bv[16];
#pragma unroll
      for (int j = 0; j < 16; ++j) bv[j] = bq[(size_t)j * DM];
      bf16x8 w0 = { f2bf(bv[0]), f2bf(bv[1]), f2bf(bv[2]), f2bf(bv[3]),
                    f2bf(bv[4]), f2bf(bv[5]), f2bf(bv[6]), f2bf(bv[7]) };
      bf16x8 w1 = { f2bf(bv[8]), f2bf(bv[9]), f2bf(bv[10]), f2bf(bv[11]),
                    f2bf(bv[12]), f2bf(bv[13]), f2bf(bv[14]), f2bf(bv[15]) };
      const int bsw = bn & 7;
      *(bf16x8*)&Bt[bn * 64 + ((wid * 2)     ^ bsw) * 8] = w0;
      *(bf16x8*)&Bt[bn * 64 + ((wid * 2 + 1) ^ bsw) * 8] = w1;
    }
    __syncthreads();
#pragma unroll
    for (int kh = 0; kh < 2; ++kh) {
      const int kq = kh * 4 + (lane >> 4);
      const int co = (kq ^ (lane & 7)) * 8;
      bf16x8 a[4], b[4];
#pragma unroll
      for (int m = 0; m < 4; ++m)
        a[m] = *(const bf16x8*)&As[(wm * 64 + m * 16 + (lane & 15)) * 64 + co];
#pragma unroll
      for (int n = 0; n < 4; ++n)
        b[n] = *(const bf16x8*)&Bt[(wn * 64 + n * 16 + (lane & 15)) * 64 + co];
#pragma unroll
      for (int m = 0; m < 4; ++m)
#pragma unroll
        for (int n = 0; n < 4; ++n)
          acc[m][n] = __builtin_amdgcn_mfma_f32_16x16x32_bf16(a[m], b[n], acc[m][n], 0, 0, 0);
    }
    __syncthreads();
  }
  float* obase = yd + (size_t)(e * CAP + mt * 128) * DM + nt * 128;
#pragma unroll
  for (int m = 0; m < 4; ++m)
#pragma unroll
    for (int n = 0; n < 4; ++n)
#pragma unroll
      for (int j = 0; j < 4; ++j) {
        int rl = wm * 64 + m * 16 + (lane >> 4) * 4 + j;
        int cl = wn * 64 + n * 16 + (lane & 15);
        obase[(size_t)rl * DM + cl] = acc[m][n][j];
      }
}

// ---------------- combine: out[t] = sum_k w_k * yd[slot_k] ----------------
__global__ __launch_bounds__(256) void k_combine(const int* __restrict__ comb_slot,
                                                 const float* __restrict__ topw,
                                                 const float* __restrict__ yd,
                                                 float* __restrict__ out) {
  int t = blockIdx.x;
  int c = threadIdx.x * 4;
  f32x4 acc = (f32x4)0.f;
#pragma unroll
  for (int j = 0; j < 2; ++j) {
    int s = comb_slot[2 * t + j];
    if (s >= 0) {
      float w = topw[2 * t + j];
      f32x4 v = *(const f32x4*)(yd + (size_t)s * DM + c);
      acc += w * v;
    }
  }
  *(f32x4*)(out + (size_t)t * DM + c) = acc;
}

extern "C" void kernel_launch(void* const* d_in, const int* in_sizes, int n_in,
                              void* d_out, int out_size, void* d_ws, size_t ws_size,
                              hipStream_t stream) {
  const float* hidden = (const float*)d_in[0];
  const int*   idx    = (const int*)d_in[1];
  const float* topw   = (const float*)d_in[2];
  const float* gup    = (const float*)d_in[3];
  const float* down   = (const float*)d_in[4];
  float* out = (float*)d_out;

  char* ws = (char*)d_ws;
  int*   slot_token = (int*)ws;                                   // E*C   = 128KB
  int*   comb_slot  = (int*)(ws + 131072);                        // N     = 64KB
  short* xd  = (short*)(ws + 131072 + 65536);                     // 64MB bf16
  short* act = xd + (size_t)NEXP * CAP * DM;                      // 64MB bf16
  float* yd  = (float*)(act + (size_t)NEXP * CAP * DFF);          // 128MB f32

  k_route<<<NEXP, 256, 0, stream>>>(idx, slot_token, comb_slot);
  k_dispatch<<<NEXP * CAP, 256, 0, stream>>>(hidden, slot_token, xd);
  k_gemm1<<<NEXP * 64, 256, 0, stream>>>(xd, gup, act);
  k_gemm2<<<NEXP * 32, 256, 0, stream>>>(act, down, yd);
  k_combine<<<NTOK, 256, 0, stream>>>(comb_slot, topw, yd, out);
}